// Round 1
// baseline (157.129 us; speedup 1.0000x reference)
//
#include <hip/hip_runtime.h>
#include <math.h>

// Problem: n=1024, raw=128, d=128, h=256
//   z = x @ W_enc + b_enc                  [1024,128]
//   A = z @ W1[:128]                       [1024,256]
//   B = z @ W1[128:] + b1                  [1024,256]  (b1 folded in)
//   out[i,j] = hard_sigmoid( sum_k selu(A[j,k]+B[i,k]) * W2[k] + b2 )

#define N_TOK 1024
#define RAW 128
#define DLAT 128
#define HDIM 256

__device__ __forceinline__ float selu_f(float t) {
    const float kScale = 1.0507009873554805f;
    const float kAlphaScale = 1.7580993408473766f; // scale*alpha
    float e = __expf(t);
    return t > 0.0f ? kScale * t : kAlphaScale * (e - 1.0f);
}

// z[n,c] = sum_k x[n,k] * W_enc[k,c] + b_enc[c]
__global__ __launch_bounds__(256) void enc_kernel(
    const float* __restrict__ x, const float* __restrict__ W_enc,
    const float* __restrict__ b_enc, float* __restrict__ z) {
    int idx = blockIdx.x * 256 + threadIdx.x;      // 1024*128 total
    int n = idx >> 7, c = idx & 127;
    const float* xr = x + n * RAW;
    float acc = b_enc[c];
#pragma unroll 8
    for (int k = 0; k < RAW; ++k)
        acc = fmaf(xr[k], W_enc[k * DLAT + c], acc);
    z[idx] = acc;
}

// A[n,c] = sum_k z[n,k]*W1[k,c]; B[n,c] = sum_k z[n,k]*W1[128+k,c] + b1[c]
// 4 rows per thread to reuse the W1 column value.
__global__ __launch_bounds__(256) void ab_kernel(
    const float* __restrict__ z, const float* __restrict__ W1,
    const float* __restrict__ b1, float* __restrict__ A, float* __restrict__ B) {
    int idx = blockIdx.x * 256 + threadIdx.x;      // (1024/4)*512 total
    int c = idx & 511;
    int n0 = (idx >> 9) << 2;
    const float* zb = z + n0 * DLAT;
    const float* w;
    float bias;
    float* dst;
    if (c < 256) { w = W1 + c; bias = 0.0f; dst = A + n0 * HDIM + c; }
    else {
        int cc = c - 256;
        w = W1 + 128 * HDIM + cc; bias = b1[cc]; dst = B + n0 * HDIM + cc;
    }
    float a0 = 0.f, a1 = 0.f, a2 = 0.f, a3 = 0.f;
#pragma unroll 4
    for (int k = 0; k < DLAT; ++k) {
        float wv = w[k * HDIM];
        a0 = fmaf(zb[k], wv, a0);
        a1 = fmaf(zb[DLAT + k], wv, a1);
        a2 = fmaf(zb[2 * DLAT + k], wv, a2);
        a3 = fmaf(zb[3 * DLAT + k], wv, a3);
    }
    dst[0] = a0 + bias;
    dst[HDIM] = a1 + bias;
    dst[2 * HDIM] = a2 + bias;
    dst[3 * HDIM] = a3 + bias;
}

// Main pair kernel: 64x64 output tile per block, 256 threads, 4x4 register tile.
// LDS holds A/B tiles K-major (transposed) with XOR-4 column swizzle:
//   phys col = j ^ (k & 60). Compute-loop b128 reads land 2-way (free).
// K processed in 2 chunks of 128 so static LDS = exactly 64 KB.
__global__ __launch_bounds__(256) void pair_kernel(
    const float* __restrict__ Ag, const float* __restrict__ Bg,
    const float* __restrict__ W2, const float* __restrict__ b2,
    float* __restrict__ out) {
    __shared__ float As[128 * 64];   // [k_local][j^swz]
    __shared__ float Bs[128 * 64];   // [k_local][i^swz]

    int t = threadIdx.x;
    int bj = blockIdx.x, bi = blockIdx.y;
    int bj64 = bj << 6, bi64 = bi << 6;

    int tj4 = (t & 15) << 2;   // j quad within tile
    int ti4 = (t >> 4) << 2;   // i quad within tile

    float acc[4][4];
#pragma unroll
    for (int i = 0; i < 4; ++i)
#pragma unroll
        for (int j = 0; j < 4; ++j) acc[i][j] = 0.0f;

    // staging lane mapping
    int kc = t & 31;           // float4-chunk along k (32 chunks = 128 floats)
    int jb = t >> 5;           // row group
    int swz_w = (kc & 15) << 2;
    int kbase = kc << 8;       // (kc*4 rows) * 64 cols

    for (int ch = 0; ch < 2; ++ch) {
        if (ch) __syncthreads();   // protect LDS reuse
        size_t koff = (size_t)(ch << 7) + (kc << 2);
#pragma unroll
        for (int p = 0; p < 8; ++p) {
            int j = jb + (p << 3);
            float4 va = *(const float4*)(Ag + (((size_t)(bj64 + j)) << 8) + koff);
            float4 vb = *(const float4*)(Bg + (((size_t)(bi64 + j)) << 8) + koff);
            int col = j ^ swz_w;
            As[kbase + col] = va.x;
            As[kbase + 64 + col] = va.y;
            As[kbase + 128 + col] = va.z;
            As[kbase + 192 + col] = va.w;
            Bs[kbase + col] = vb.x;
            Bs[kbase + 64 + col] = vb.y;
            Bs[kbase + 128 + col] = vb.z;
            Bs[kbase + 192 + col] = vb.w;
        }
        __syncthreads();

        const float* W2c = W2 + (ch << 7);
#pragma unroll 4
        for (int k = 0; k < 128; ++k) {
            int sw = k & 60;
            float4 av = *(const float4*)&As[(k << 6) + (tj4 ^ sw)];
            float4 bv = *(const float4*)&Bs[(k << 6) + (ti4 ^ sw)];
            float w = W2c[k];   // uniform index -> scalar load, L1-hot
            float a_[4] = {av.x, av.y, av.z, av.w};
            float b_[4] = {bv.x, bv.y, bv.z, bv.w};
#pragma unroll
            for (int i = 0; i < 4; ++i)
#pragma unroll
            for (int j = 0; j < 4; ++j) {
                float s = selu_f(a_[j] + b_[i]);
                acc[i][j] = fmaf(s, w, acc[i][j]);
            }
        }
    }

    // epilogue: hard_sigmoid(s + b2) = clamp(s/6 + (b2+3)/6, 0, 1)
    float b2v = b2[0];
    size_t obase = ((size_t)(bi64 + ti4) << 10) + (size_t)(bj64 + tj4);
#pragma unroll
    for (int i = 0; i < 4; ++i) {
        float4 o;
        o.x = __saturatef((acc[i][0] + b2v) * (1.0f / 6.0f) + 0.5f);
        o.y = __saturatef((acc[i][1] + b2v) * (1.0f / 6.0f) + 0.5f);
        o.z = __saturatef((acc[i][2] + b2v) * (1.0f / 6.0f) + 0.5f);
        o.w = __saturatef((acc[i][3] + b2v) * (1.0f / 6.0f) + 0.5f);
        *(float4*)(out + obase + ((size_t)i << 10)) = o;
    }
}

extern "C" void kernel_launch(void* const* d_in, const int* in_sizes, int n_in,
                              void* d_out, int out_size, void* d_ws, size_t ws_size,
                              hipStream_t stream) {
    const float* x     = (const float*)d_in[0];
    const float* W_enc = (const float*)d_in[1];
    const float* b_enc = (const float*)d_in[2];
    const float* W1    = (const float*)d_in[3];
    const float* b1    = (const float*)d_in[4];
    const float* W2    = (const float*)d_in[5];
    const float* b2    = (const float*)d_in[6];
    float* out = (float*)d_out;

    char* ws = (char*)d_ws;
    float* z = (float*)(ws);                          // 1024*128*4 = 512 KB
    float* A = (float*)(ws + 512 * 1024);             // 1024*256*4 = 1 MB
    float* B = (float*)(ws + 512 * 1024 + 1024 * 1024); // 1 MB

    enc_kernel<<<512, 256, 0, stream>>>(x, W_enc, b_enc, z);
    ab_kernel<<<512, 256, 0, stream>>>(z, W1, b1, A, B);
    pair_kernel<<<dim3(16, 16), 256, 0, stream>>>(A, B, W2, b2, out);
}

// Round 2
// 136.157 us; speedup vs baseline: 1.1540x; 1.1540x over previous
//
#include <hip/hip_runtime.h>
#include <math.h>

// n=1024, raw=128, d=128, h=256
// Reformulation:
//   Wc = [W_enc @ W1[:d] | W_enc @ W1[d:]] * log2e      [128, 512]
//   biasc = [b_enc@W1[:d] | b_enc@W1[d:] + b1] * log2e  [512]
//   AB = x @ Wc + biasc            [1024, 512]  (cols 0..255 = A', 256..511 = B')
//   (A', B' are log2e-prescaled preactivation halves)
//   t' = A'[j,k] + B'[i,k]  (= log2e * t)
//   selu(t)*w summed over k:
//     acc1 = sum w_k * max(t',0)    -> * (s/log2e)
//     acc2 = sum w_k * exp2(min(t',0))  -> * (s*alpha)
//     result = hsig( s/log2e*acc1 + s*alpha*acc2 - s*alpha*sum(w) + b2 )

#define LOG2E       1.4426950408889634f
#define SELU_AS     1.7580993408473766f   // scale*alpha
#define S_OVER_L2E  0.7282921587620419f   // scale/log2e

// ws layout (floats): Wc @0 (65536), biasc @65536 (512), S @66048, AB @66560 (524288)

__global__ __launch_bounds__(256) void prep_kernel(
    const float* __restrict__ W_enc, const float* __restrict__ b_enc,
    const float* __restrict__ W1, const float* __restrict__ b1,
    const float* __restrict__ W2, float* __restrict__ Wc,
    float* __restrict__ biasc, float* __restrict__ Sval) {
    int b = blockIdx.x, t = threadIdx.x;
    if (b < 256) {
        int k_raw = b >> 1;
        int c = ((b & 1) << 8) + t;           // 0..511
        int off = (c < 256) ? 0 : 128;
        int cc = c & 255;
        const float* we = W_enc + k_raw * 128;
        const float* w1 = W1 + off * 256 + cc;
        float acc = 0.f;
#pragma unroll 8
        for (int dl = 0; dl < 128; ++dl)
            acc = fmaf(we[dl], w1[dl * 256], acc);
        Wc[k_raw * 512 + c] = acc * LOG2E;
    } else {
        // biases for c=t and c=t+256, plus S = sum(W2)
        float acc0 = 0.f, acc1 = b1[t];
        const float* w1a = W1 + t;
        const float* w1b = W1 + 128 * 256 + t;
#pragma unroll 8
        for (int dl = 0; dl < 128; ++dl) {
            float be = b_enc[dl];
            acc0 = fmaf(be, w1a[dl * 256], acc0);
            acc1 = fmaf(be, w1b[dl * 256], acc1);
        }
        biasc[t] = acc0 * LOG2E;
        biasc[t + 256] = acc1 * LOG2E;
        if (t < 64) {
            float s = W2[t] + W2[t + 64] + W2[t + 128] + W2[t + 192];
#pragma unroll
            for (int o = 32; o > 0; o >>= 1) s += __shfl_down(s, o);
            if (t == 0) Sval[0] = s;
        }
    }
}

// AB[n, c] = sum_k x[n,k] * Wc[k,c] + biasc[c]; 4 rows per thread.
__global__ __launch_bounds__(256) void ab_kernel(
    const float* __restrict__ x, const float* __restrict__ Wc,
    const float* __restrict__ biasc, float* __restrict__ AB) {
    int idx = blockIdx.x * 256 + threadIdx.x;   // 512 blocks
    int c = idx & 511;
    int n0 = (idx >> 9) << 2;
    const float* xb = x + n0 * 128;             // uniform per block -> s_load
    float bias = biasc[c];
    float a0 = bias, a1 = bias, a2 = bias, a3 = bias;
    const float* w = Wc + c;
#pragma unroll 4
    for (int k = 0; k < 128; ++k) {
        float wv = w[k * 512];
        a0 = fmaf(xb[k], wv, a0);
        a1 = fmaf(xb[128 + k], wv, a1);
        a2 = fmaf(xb[256 + k], wv, a2);
        a3 = fmaf(xb[384 + k], wv, a3);
    }
    AB[(size_t)(n0 + 0) * 512 + c] = a0;
    AB[(size_t)(n0 + 1) * 512 + c] = a1;
    AB[(size_t)(n0 + 2) * 512 + c] = a2;
    AB[(size_t)(n0 + 3) * 512 + c] = a3;
}

// 32x32 output tile per block, 256 threads, 2x2 per thread.
// Grid (32,32) = 1024 blocks x 4 waves = 4096 waves = 16 waves/CU.
// LDS k-major [k][col], row stride 32 floats -> col==bank, compute reads
// (16 distinct float2 per wave) cover all 32 banks exactly once.
__global__ __launch_bounds__(256, 4) void pair_kernel(
    const float* __restrict__ AB, const float* __restrict__ W2,
    const float* __restrict__ b2, const float* __restrict__ Sval,
    float* __restrict__ out) {
    __shared__ float As[64 * 32];
    __shared__ float Bs[64 * 32];
    int t = threadIdx.x;
    int bj32 = blockIdx.x << 5, bi32 = blockIdx.y << 5;
    // staging map: r = row within tile, kq*8 = k offset
    int r = t >> 3, kq = t & 7;
    // compute map
    int tj = (t & 15) << 1, ti = (t >> 4) << 1;

    float acc1[2][2] = {{0.f, 0.f}, {0.f, 0.f}};
    float acc2[2][2] = {{0.f, 0.f}, {0.f, 0.f}};

    const float* arow = AB + (size_t)(bj32 + r) * 512 + (kq << 3);
    const float* brow = AB + (size_t)(bi32 + r) * 512 + 256 + (kq << 3);
    int sb = (kq << 3) * 32 + r;

    for (int ch = 0; ch < 4; ++ch) {
        if (ch) __syncthreads();
        float4 va1 = *(const float4*)(arow + (ch << 6));
        float4 va2 = *(const float4*)(arow + (ch << 6) + 4);
        float4 vb1 = *(const float4*)(brow + (ch << 6));
        float4 vb2 = *(const float4*)(brow + (ch << 6) + 4);
        As[sb +   0] = va1.x; As[sb +  32] = va1.y;
        As[sb +  64] = va1.z; As[sb +  96] = va1.w;
        As[sb + 128] = va2.x; As[sb + 160] = va2.y;
        As[sb + 192] = va2.z; As[sb + 224] = va2.w;
        Bs[sb +   0] = vb1.x; Bs[sb +  32] = vb1.y;
        Bs[sb +  64] = vb1.z; Bs[sb +  96] = vb1.w;
        Bs[sb + 128] = vb2.x; Bs[sb + 160] = vb2.y;
        Bs[sb + 192] = vb2.z; Bs[sb + 224] = vb2.w;
        __syncthreads();

        const float* W2c = W2 + (ch << 6);
#pragma unroll 8
        for (int k = 0; k < 64; ++k) {
            float w = W2c[k];                       // uniform -> s_load
            float2 av = *(const float2*)&As[(k << 5) + tj];
            float2 bv = *(const float2*)&Bs[(k << 5) + ti];
            float aa[2] = {av.x, av.y};
            float bb[2] = {bv.x, bv.y};
#pragma unroll
            for (int i = 0; i < 2; ++i)
#pragma unroll
            for (int j = 0; j < 2; ++j) {
                float tt = aa[j] + bb[i];
                float m = fmaxf(tt, 0.f);
                float n = fminf(tt, 0.f);
                float e = __builtin_amdgcn_exp2f(n);    // raw v_exp_f32
                acc1[i][j] = fmaf(w, m, acc1[i][j]);
                acc2[i][j] = fmaf(w, e, acc2[i][j]);
            }
        }
    }

    float base = b2[0] - SELU_AS * Sval[0];
    size_t orow = ((size_t)(bi32 + ti) << 10) + (size_t)(bj32 + tj);
#pragma unroll
    for (int i = 0; i < 2; ++i) {
        float v0 = fmaf(S_OVER_L2E, acc1[i][0], fmaf(SELU_AS, acc2[i][0], base));
        float v1 = fmaf(S_OVER_L2E, acc1[i][1], fmaf(SELU_AS, acc2[i][1], base));
        float2 o;
        o.x = __saturatef(v0 * (1.0f / 6.0f) + 0.5f);
        o.y = __saturatef(v1 * (1.0f / 6.0f) + 0.5f);
        *(float2*)(out + orow + ((size_t)i << 10)) = o;
    }
}

extern "C" void kernel_launch(void* const* d_in, const int* in_sizes, int n_in,
                              void* d_out, int out_size, void* d_ws, size_t ws_size,
                              hipStream_t stream) {
    const float* x     = (const float*)d_in[0];
    const float* W_enc = (const float*)d_in[1];
    const float* b_enc = (const float*)d_in[2];
    const float* W1    = (const float*)d_in[3];
    const float* b1    = (const float*)d_in[4];
    const float* W2    = (const float*)d_in[5];
    const float* b2    = (const float*)d_in[6];
    float* out = (float*)d_out;

    float* ws = (float*)d_ws;
    float* Wc    = ws;            // 65536
    float* biasc = ws + 65536;    // 512
    float* Sval  = ws + 66048;    // 1
    float* AB    = ws + 66560;    // 524288

    prep_kernel<<<257, 256, 0, stream>>>(W_enc, b_enc, W1, b1, W2, Wc, biasc, Sval);
    ab_kernel<<<512, 256, 0, stream>>>(x, Wc, biasc, AB);
    pair_kernel<<<dim3(32, 32), 256, 0, stream>>>(AB, W2, b2, Sval, out);
}